// Round 7
// baseline (2397.977 us; speedup 1.0000x reference)
//
#include <hip/hip_runtime.h>
#include <cstdint>
#include <cstddef>

// Problem constants
#define BDIM 2
#define CDIM 512
#define HDIM 128
#define WDIM 128
#define NDIM (HDIM * WDIM)        // 16384
#define LNUM 6
#define NHEADS 8
#define HEAD_DIM 64
#define NPTS 4
#define BN_TOT (BDIM * NDIM)      // 32768

typedef unsigned short u16;
typedef __attribute__((ext_vector_type(8))) short bf16x8;   // 8 bf16 = 4 VGPRs
typedef __attribute__((ext_vector_type(4))) float f32x4;    // MFMA accum

__device__ __forceinline__ u16 f2bf(float x) {              // RNE fp32->bf16
    unsigned u = __float_as_uint(x);
    u += 0x7fffu + ((u >> 16) & 1u);
    return (u16)(u >> 16);
}
__device__ __forceinline__ float bf2f(u16 h) {
    return __uint_as_float(((unsigned)h) << 16);
}

// load 8 bf16 (16B) directly global -> VGPR as MFMA operand
__device__ __forceinline__ bf16x8 ldfrag(const u16* p) {
    return *(const bf16x8*)p;
}

// fused (q + qpos) fragment: unpack bf16 pairs, add, repack
__device__ __forceinline__ bf16x8 addpack(const u16* qp, const u16* pp) {
    uint4 a = *(const uint4*)qp;
    uint4 b = *(const uint4*)pp;
    unsigned aw[4] = {a.x, a.y, a.z, a.w};
    unsigned bw[4] = {b.x, b.y, b.z, b.w};
    union { unsigned u[4]; bf16x8 h; } r;
#pragma unroll
    for (int k = 0; k < 4; ++k) {
        float lo = bf2f((u16)(aw[k] & 0xffff)) + bf2f((u16)(bw[k] & 0xffff));
        float hi = bf2f((u16)(aw[k] >> 16)) + bf2f((u16)(bw[k] >> 16));
        r.u[k] = (unsigned)f2bf(lo) | ((unsigned)f2bf(hi) << 16);
    }
    return r.h;
}

// ---------------------------------------------------------------------------
// voxelization: mask / order / ref / pack_q(bf16)
// ---------------------------------------------------------------------------
__global__ void mask_kernel(const float* __restrict__ lidar, int* __restrict__ mask)
{
    int idx = blockIdx.x * blockDim.x + threadIdx.x;
    if (idx >= BN_TOT) return;
    int b = idx / NDIM;
    int n = idx - b * NDIM;
    const float* p = lidar + (size_t)b * CDIM * NDIM + n;
    int ok = 1;
#pragma unroll 8
    for (int c = 0; c < CDIM; ++c)
        ok &= (p[(size_t)c * NDIM] != 0.0f);
    mask[idx] = ok;
}

__global__ void order_kernel(const int* __restrict__ mask, int* __restrict__ order,
                             int* __restrict__ nvalid)
{
    int b = blockIdx.x;
    const int* m = mask + b * NDIM;
    int* ord = order + b * NDIM;
    __shared__ int part[256];
    __shared__ int totalValid;
    int t = threadIdx.x;
    const int CHUNK = NDIM / 256;
    int base = t * CHUNK;
    int cnt = 0;
    for (int i = 0; i < CHUNK; ++i) cnt += m[base + i];
    part[t] = cnt;
    __syncthreads();
    for (int s = 1; s < 256; s <<= 1) {
        int v = (t >= s) ? part[t - s] : 0;
        __syncthreads();
        part[t] += v;
        __syncthreads();
    }
    if (t == 255) { totalValid = part[255]; nvalid[b] = part[255]; }
    __syncthreads();
    int validBefore = (t == 0) ? 0 : part[t - 1];
    int nv = totalValid;
    for (int i = 0; i < CHUNK; ++i) {
        int n = base + i;
        if (m[n]) { ord[validBefore] = n; validBefore++; }
        else      { int invBefore = n - validBefore; ord[nv + invBefore] = n; }
    }
}

__global__ void ref_kernel(const int* __restrict__ order, const int* __restrict__ nvalid,
                           float* __restrict__ ref)
{
    int idx = blockIdx.x * blockDim.x + threadIdx.x;
    if (idx >= BN_TOT) return;
    int b = idx / NDIM;
    int j = idx - b * NDIM;
    int n = order[idx];
    float flag = (j < nvalid[b]) ? 1.0f : 0.0f;
    int hh = n / WDIM;
    int ww = n - hh * WDIM;
    ref[(size_t)idx * 2 + 0] = ((float)ww / (float)WDIM) * flag;
    ref[(size_t)idx * 2 + 1] = ((float)hh / (float)HDIM) * flag;
}

__global__ void pack_q_kernel(const float* __restrict__ lidar, const int* __restrict__ order,
                              const int* __restrict__ nvalid, u16* __restrict__ q)
{
    __shared__ float tile[32][33];
    __shared__ int ord_s[32];
    int b  = blockIdx.z;
    int j0 = blockIdx.x * 32;
    int c0 = blockIdx.y * 32;
    int tx = threadIdx.x, ty = threadIdx.y;
    if (ty == 0) ord_s[tx] = order[b * NDIM + j0 + tx];
    __syncthreads();
    const float* src = lidar + (size_t)b * CDIM * NDIM;
#pragma unroll
    for (int k = 0; k < 4; ++k) {
        int cl = ty * 4 + k;
        tile[cl][tx] = src[(size_t)(c0 + cl) * NDIM + ord_s[tx]];
    }
    __syncthreads();
    int nv = nvalid[b];
#pragma unroll
    for (int k = 0; k < 4; ++k) {
        int jl = ty * 4 + k;
        int j = j0 + jl;
        float f = (j < nv) ? 1.0f : 0.0f;
        q[((size_t)b * NDIM + j) * CDIM + c0 + tx] = f2bf(tile[tx][jl] * f);
    }
}

// final scatter: out[b,c,order[j]] = q(bf16)[b,j,c] * valid  (fp32 out)
__global__ void scatter_kernel(const u16* __restrict__ q, const int* __restrict__ order,
                               const int* __restrict__ nvalid, float* __restrict__ out)
{
    __shared__ float tile[32][33];
    __shared__ int ord_s[32];
    int b  = blockIdx.z;
    int j0 = blockIdx.x * 32;
    int c0 = blockIdx.y * 32;
    int tx = threadIdx.x, ty = threadIdx.y;
    if (ty == 0) ord_s[tx] = order[b * NDIM + j0 + tx];
    __syncthreads();
    int nv = nvalid[b];
#pragma unroll
    for (int k = 0; k < 4; ++k) {
        int jl = ty * 4 + k;
        int j = j0 + jl;
        float f = (j < nv) ? 1.0f : 0.0f;
        tile[jl][tx] = bf2f(q[((size_t)b * NDIM + j) * CDIM + c0 + tx]) * f;
    }
    __syncthreads();
    float* dst = out + (size_t)b * CDIM * NDIM;
#pragma unroll
    for (int k = 0; k < 4; ++k) {
        int cl = ty * 4 + k;
        dst[(size_t)(c0 + cl) * NDIM + ord_s[tx]] = tile[tx][cl];
    }
}

// ---------------------------------------------------------------------------
// batched weight transpose-convert: src fp32 [z][512][512] -> dst bf16 [z][N][K]
// ---------------------------------------------------------------------------
__global__ void tconv_b_kernel(const float* __restrict__ src0, u16* __restrict__ dst0)
{
    __shared__ float t[32][33];
    int z = blockIdx.z;
    const float* src = src0 + (size_t)z * 512 * 512;
    u16* dst = dst0 + (size_t)z * 512 * 512;
    int k0 = blockIdx.x * 32, n0 = blockIdx.y * 32;
    int tx = threadIdx.x, ty = threadIdx.y;
#pragma unroll
    for (int j = 0; j < 4; ++j) {
        int kl = ty * 4 + j;
        t[kl][tx] = src[(size_t)(k0 + kl) * 512 + n0 + tx];
    }
    __syncthreads();
#pragma unroll
    for (int j = 0; j < 4; ++j) {
        int nl = ty * 4 + j;
        dst[(size_t)(n0 + nl) * 512 + k0 + tx] = f2bf(t[tx][nl]);
    }
}

// batched: Woff [z][512][64] + Waw [z][512][32] -> dst bf16 [z][96][512]
__global__ void tconv_offaw_b_kernel(const float* __restrict__ woff0,
                                     const float* __restrict__ waw0,
                                     u16* __restrict__ dst0)
{
    __shared__ float t[32][33];
    int z = blockIdx.z;
    const float* woff = woff0 + (size_t)z * 512 * 64;
    const float* waw  = waw0 + (size_t)z * 512 * 32;
    u16* dst = dst0 + (size_t)z * 96 * 512;
    int k0 = blockIdx.x * 32, n0 = blockIdx.y * 32;
    int tx = threadIdx.x, ty = threadIdx.y;
#pragma unroll
    for (int j = 0; j < 4; ++j) {
        int kl = ty * 4 + j;
        int n = n0 + tx;
        float v = (n < 64) ? woff[(size_t)(k0 + kl) * 64 + n]
                           : waw[(size_t)(k0 + kl) * 32 + (n - 64)];
        t[kl][tx] = v;
    }
    __syncthreads();
#pragma unroll
    for (int j = 0; j < 4; ++j) {
        int nl = ty * 4 + j;
        dst[(size_t)(n0 + nl) * 512 + k0 + tx] = f2bf(t[tx][nl]);
    }
}

// bev (B,C,N) fp32 -> featT (B,N,C) bf16
__global__ void bev_conv_kernel(const float* __restrict__ bev, u16* __restrict__ dst)
{
    __shared__ float t[32][33];
    int b  = blockIdx.z;
    int n0 = blockIdx.x * 32;
    int c0 = blockIdx.y * 32;
    int tx = threadIdx.x, ty = threadIdx.y;
    const float* src = bev + (size_t)b * CDIM * NDIM;
#pragma unroll
    for (int j = 0; j < 4; ++j) {
        int cl = ty * 4 + j;
        t[cl][tx] = src[(size_t)(c0 + cl) * NDIM + n0 + tx];
    }
    __syncthreads();
#pragma unroll
    for (int j = 0; j < 4; ++j) {
        int nl = ty * 4 + j;
        dst[((size_t)b * NDIM + n0 + nl) * CDIM + c0 + tx] = f2bf(t[tx][nl]);
    }
}

// ---------------------------------------------------------------------------
// PE hidden: h = relu(BN(ref @ pe_W1))  -> bf16
// ---------------------------------------------------------------------------
__global__ void pe_hidden_kernel(const float* __restrict__ ref, const float* __restrict__ W1,
                                 const float* __restrict__ g, const float* __restrict__ bb,
                                 const float* __restrict__ m, const float* __restrict__ v,
                                 u16* __restrict__ out)
{
    int row = blockIdx.x;
    float r0 = ref[(size_t)row * 2 + 0];
    float r1 = ref[(size_t)row * 2 + 1];
    for (int c = threadIdx.x; c < CDIM; c += blockDim.x) {
        float pe = r0 * W1[c] + r1 * W1[CDIM + c];
        pe = (pe - m[c]) * rsqrtf(v[c] + 1e-5f) * g[c] + bb[c];
        out[(size_t)row * CDIM + c] = f2bf(fmaxf(pe, 0.0f));
    }
}

// ---------------------------------------------------------------------------
// LDS-free MFMA bf16 GEMM: C[M][512] = A[M][512] @ Bt[512][512]^T, bf16 out.
// 128x128 block (4 waves, each 64x64). Operand fragments loaded directly
// global->VGPR (no LDS, no barriers in K-loop).
// ---------------------------------------------------------------------------
__global__ __launch_bounds__(256) void gemm_bf16(
    const u16* __restrict__ A, const u16* __restrict__ Bt,
    const float* __restrict__ bias, u16* __restrict__ outB, int relu)
{
    int tid = threadIdx.x;
    int wv = tid >> 6, lane = tid & 63;
    int wr = wv >> 1, wc = wv & 1;
    int quad = lane >> 4, l15 = lane & 15;
    int bm = blockIdx.y * 128, bn = blockIdx.x * 128;

    const u16* Ap[4];
    const u16* Bp[4];
#pragma unroll
    for (int mi = 0; mi < 4; ++mi)
        Ap[mi] = A + (size_t)(bm + wr * 64 + mi * 16 + l15) * 512 + quad * 8;
#pragma unroll
    for (int ni = 0; ni < 4; ++ni)
        Bp[ni] = Bt + (size_t)(bn + wc * 64 + ni * 16 + l15) * 512 + quad * 8;

    f32x4 acc[4][4];
#pragma unroll
    for (int i = 0; i < 4; ++i)
#pragma unroll
        for (int j = 0; j < 4; ++j) { f32x4 z = {0.f, 0.f, 0.f, 0.f}; acc[i][j] = z; }

#pragma unroll
    for (int it = 0; it < 16; ++it) {
        int k0 = it * 32;
        bf16x8 av[4], bv[4];
#pragma unroll
        for (int mi = 0; mi < 4; ++mi) av[mi] = ldfrag(Ap[mi] + k0);
#pragma unroll
        for (int ni = 0; ni < 4; ++ni) bv[ni] = ldfrag(Bp[ni] + k0);
#pragma unroll
        for (int mi = 0; mi < 4; ++mi)
#pragma unroll
            for (int ni = 0; ni < 4; ++ni)
                acc[mi][ni] = __builtin_amdgcn_mfma_f32_16x16x32_bf16(
                    av[mi], bv[ni], acc[mi][ni], 0, 0, 0);
    }

    int rowb = bm + wr * 64;
    int colb = bn + wc * 64;
#pragma unroll
    for (int mi = 0; mi < 4; ++mi) {
#pragma unroll
        for (int ni = 0; ni < 4; ++ni) {
            int col = colb + ni * 16 + l15;
            float bi = bias ? bias[col] : 0.0f;
#pragma unroll
            for (int r = 0; r < 4; ++r) {
                int row = rowb + mi * 16 + quad * 4 + r;
                float val = acc[mi][ni][r] + bi;
                if (relu) val = fmaxf(val, 0.0f);
                outB[(size_t)row * 512 + col] = f2bf(val);
            }
        }
    }
}

// ---------------------------------------------------------------------------
// LDS-free fused GEMM + residual + LayerNorm:
//   BM=64, BN=512 (full row), 512 threads (8 waves, wave wv = cols wv*64..+64)
//   q_out = LN(A@Bt^T + bias + resid)
// ---------------------------------------------------------------------------
__global__ __launch_bounds__(512) void gemm_ln(
    const u16* __restrict__ A, const u16* __restrict__ Bt,
    const float* __restrict__ bias, const u16* __restrict__ resid,
    const float* __restrict__ g, const float* __restrict__ bta,
    u16* __restrict__ outQ)
{
    __shared__ float rs[8][64];
    __shared__ float rq[8][64];
    __shared__ float muL[64], invL[64];

    int tid = threadIdx.x;
    int wv = tid >> 6, lane = tid & 63;
    int quad = lane >> 4, l15 = lane & 15;
    int bm = blockIdx.x * 64;

    const u16* Ap[4];
    const u16* Bp[4];
#pragma unroll
    for (int mi = 0; mi < 4; ++mi)
        Ap[mi] = A + (size_t)(bm + mi * 16 + l15) * 512 + quad * 8;
#pragma unroll
    for (int ni = 0; ni < 4; ++ni)
        Bp[ni] = Bt + (size_t)(wv * 64 + ni * 16 + l15) * 512 + quad * 8;

    f32x4 acc[4][4];
#pragma unroll
    for (int i = 0; i < 4; ++i)
#pragma unroll
        for (int j = 0; j < 4; ++j) { f32x4 z = {0.f, 0.f, 0.f, 0.f}; acc[i][j] = z; }

#pragma unroll
    for (int it = 0; it < 16; ++it) {
        int k0 = it * 32;
        bf16x8 av[4], bv[4];
#pragma unroll
        for (int mi = 0; mi < 4; ++mi) av[mi] = ldfrag(Ap[mi] + k0);
#pragma unroll
        for (int ni = 0; ni < 4; ++ni) bv[ni] = ldfrag(Bp[ni] + k0);
#pragma unroll
        for (int mi = 0; mi < 4; ++mi)
#pragma unroll
            for (int ni = 0; ni < 4; ++ni)
                acc[mi][ni] = __builtin_amdgcn_mfma_f32_16x16x32_bf16(
                    av[mi], bv[ni], acc[mi][ni], 0, 0, 0);
    }

    // epilogue: val = acc + bias + resid
    int colb = wv * 64;
    float biasv[4], gv[4], btv[4];
#pragma unroll
    for (int ni = 0; ni < 4; ++ni) {
        int c = colb + ni * 16 + l15;
        biasv[ni] = bias ? bias[c] : 0.0f;
        gv[ni] = g[c];
        btv[ni] = bta[c];
    }
#pragma unroll
    for (int mi = 0; mi < 4; ++mi) {
#pragma unroll
        for (int r = 0; r < 4; ++r) {
            size_t rowoff = (size_t)(bm + mi * 16 + quad * 4 + r) * 512;
#pragma unroll
            for (int ni = 0; ni < 4; ++ni) {
                int col = colb + ni * 16 + l15;
                acc[mi][ni][r] += biasv[ni] + bf2f(resid[rowoff + col]);
            }
        }
    }
    // row reduction: per (mi,r) sum across ni then across 16 lanes
#pragma unroll
    for (int mi = 0; mi < 4; ++mi) {
#pragma unroll
        for (int r = 0; r < 4; ++r) {
            float s = acc[mi][0][r] + acc[mi][1][r] + acc[mi][2][r] + acc[mi][3][r];
            float s2 = acc[mi][0][r] * acc[mi][0][r] + acc[mi][1][r] * acc[mi][1][r]
                     + acc[mi][2][r] * acc[mi][2][r] + acc[mi][3][r] * acc[mi][3][r];
#pragma unroll
            for (int m = 1; m < 16; m <<= 1) {
                s  += __shfl_xor(s, m, 64);
                s2 += __shfl_xor(s2, m, 64);
            }
            if (l15 == 0) {
                rs[wv][mi * 16 + quad * 4 + r] = s;
                rq[wv][mi * 16 + quad * 4 + r] = s2;
            }
        }
    }
    __syncthreads();
    if (tid < 64) {
        float s = 0.f, s2 = 0.f;
#pragma unroll
        for (int w = 0; w < 8; ++w) { s += rs[w][tid]; s2 += rq[w][tid]; }
        float mu = s * (1.0f / 512.0f);
        float var = s2 * (1.0f / 512.0f) - mu * mu;
        muL[tid] = mu;
        invL[tid] = rsqrtf(var + 1e-5f);
    }
    __syncthreads();
#pragma unroll
    for (int mi = 0; mi < 4; ++mi) {
#pragma unroll
        for (int r = 0; r < 4; ++r) {
            int lrow = mi * 16 + quad * 4 + r;
            float mu = muL[lrow], iv = invL[lrow];
            size_t rowoff = (size_t)(bm + lrow) * 512;
#pragma unroll
            for (int ni = 0; ni < 4; ++ni) {
                int col = colb + ni * 16 + l15;
                float y = (acc[mi][ni][r] - mu) * iv * gv[ni] + btv[ni];
                outQ[rowoff + col] = f2bf(y);
            }
        }
    }
}

// ---------------------------------------------------------------------------
// LDS-free fused off+aw GEMM with on-the-fly A = q + qpos:
//   (q+qpos) @ OffAwT[96][512] -> offb[M][64], awb[M][32] (bf16)
//   128 rows/block, 4 waves (wr=wv&1 rows, wc=wv>>1 cols; cols>=96 discarded)
// ---------------------------------------------------------------------------
__global__ __launch_bounds__(256) void gemm_offaw(
    const u16* __restrict__ q, const u16* __restrict__ qpos,
    const u16* __restrict__ Bt,
    const float* __restrict__ boff, const float* __restrict__ baw,
    u16* __restrict__ offb, u16* __restrict__ awb)
{
    int tid = threadIdx.x;
    int wv = tid >> 6, lane = tid & 63;
    int wr = wv & 1, wc = wv >> 1;
    int quad = lane >> 4, l15 = lane & 15;
    int bm = blockIdx.y * 128;

    const u16* Qp[4];
    const u16* Pp[4];
    const u16* Bp[4];
#pragma unroll
    for (int mi = 0; mi < 4; ++mi) {
        size_t off = (size_t)(bm + wr * 64 + mi * 16 + l15) * 512 + quad * 8;
        Qp[mi] = q + off;
        Pp[mi] = qpos + off;
    }
#pragma unroll
    for (int ni = 0; ni < 4; ++ni) {
        int brow = wc * 64 + ni * 16 + l15;
        if (brow > 95) brow = 95;               // clamp; outputs discarded
        Bp[ni] = Bt + (size_t)brow * 512 + quad * 8;
    }

    f32x4 acc[4][4];
#pragma unroll
    for (int i = 0; i < 4; ++i)
#pragma unroll
        for (int j = 0; j < 4; ++j) { f32x4 z = {0.f, 0.f, 0.f, 0.f}; acc[i][j] = z; }

#pragma unroll
    for (int it = 0; it < 16; ++it) {
        int k0 = it * 32;
        bf16x8 av[4], bv[4];
#pragma unroll
        for (int mi = 0; mi < 4; ++mi) av[mi] = addpack(Qp[mi] + k0, Pp[mi] + k0);
#pragma unroll
        for (int ni = 0; ni < 4; ++ni) bv[ni] = ldfrag(Bp[ni] + k0);
#pragma unroll
        for (int mi = 0; mi < 4; ++mi)
#pragma unroll
            for (int ni = 0; ni < 4; ++ni)
                acc[mi][ni] = __builtin_amdgcn_mfma_f32_16x16x32_bf16(
                    av[mi], bv[ni], acc[mi][ni], 0, 0, 0);
    }

    int rowb = bm + wr * 64;
#pragma unroll
    for (int mi = 0; mi < 4; ++mi) {
#pragma unroll
        for (int ni = 0; ni < 4; ++ni) {
            int col = wc * 64 + ni * 16 + l15;
            if (col < 96) {
                float bi = (col < 64) ? boff[col] : baw[col - 64];
#pragma unroll
                for (int r = 0; r < 4; ++r) {
                    int row = rowb + mi * 16 + quad * 4 + r;
                    float val = acc[mi][ni][r] + bi;
                    if (col < 64) offb[(size_t)row * 64 + col] = f2bf(val);
                    else          awb[(size_t)row * 32 + (col - 64)] = f2bf(val);
                }
            }
        }
    }
}

// ---------------------------------------------------------------------------
// deformable sampling: one wave per (b,j); lane = (head, 8 channels)
// ---------------------------------------------------------------------------
__global__ __launch_bounds__(256) void sample_kernel(
    const float* __restrict__ ref, const u16* __restrict__ off,
    const u16* __restrict__ aw, const u16* __restrict__ v,
    u16* __restrict__ out)
{
    int bj = blockIdx.x * 4 + (threadIdx.x >> 6);   // b*N + j
    int lane = threadIdx.x & 63;
    int h  = lane >> 3;
    int d8 = (lane & 7) * 8;
    int b  = bj >> 14;

    float rx = ref[(size_t)bj * 2 + 0];
    float ry = ref[(size_t)bj * 2 + 1];
    uint4 offv = *(const uint4*)(off + (size_t)bj * 64 + h * 8);
    uint2 awv  = *(const uint2*)(aw + (size_t)bj * 32 + h * 4);

    float l0 = bf2f((u16)(awv.x & 0xffff)), l1 = bf2f((u16)(awv.x >> 16));
    float l2 = bf2f((u16)(awv.y & 0xffff)), l3 = bf2f((u16)(awv.y >> 16));
    float mx = fmaxf(fmaxf(l0, l1), fmaxf(l2, l3));
    float e[4];
    e[0] = expf(l0 - mx); e[1] = expf(l1 - mx);
    e[2] = expf(l2 - mx); e[3] = expf(l3 - mx);
    float inv_es = 1.0f / (e[0] + e[1] + e[2] + e[3]);

    const u16* vb = v + (size_t)b * NDIM * CDIM + h * HEAD_DIM + d8;
    float acc[8] = {0.f, 0.f, 0.f, 0.f, 0.f, 0.f, 0.f, 0.f};
    unsigned ow[4] = {offv.x, offv.y, offv.z, offv.w};

#pragma unroll
    for (int p = 0; p < NPTS; ++p) {
        float ox = bf2f((u16)(ow[p] & 0xffff));
        float oy = bf2f((u16)(ow[p] >> 16));
        float X = rx * (float)WDIM + ox - 0.5f;
        float Y = ry * (float)HDIM + oy - 0.5f;
        float x0f = floorf(X), y0f = floorf(Y);
        float wx = X - x0f, wy = Y - y0f;
        int x0 = (int)x0f, y0 = (int)y0f;
        float ep = e[p];
#pragma unroll
        for (int cy = 0; cy < 2; ++cy) {
            int yy = y0 + cy;
            float wyc = cy ? wy : (1.0f - wy);
            int yin = (yy >= 0) & (yy < HDIM);
            int yc = min(max(yy, 0), HDIM - 1);
#pragma unroll
            for (int cx = 0; cx < 2; ++cx) {
                int xx = x0 + cx;
                float wxc = cx ? wx : (1.0f - wx);
                int xin = (xx >= 0) & (xx < WDIM);
                int xc = min(max(xx, 0), WDIM - 1);
                float wgt = ep * wyc * wxc * (float)(yin & xin);
                uint4 vv = *(const uint4*)(vb + (size_t)(yc * WDIM + xc) * CDIM);
                acc[0] += wgt * bf2f((u16)(vv.x & 0xffff));
                acc[1] += wgt * bf2f((u16)(vv.x >> 16));
                acc[2] += wgt * bf2f((u16)(vv.y & 0xffff));
                acc[3] += wgt * bf2f((u16)(vv.y >> 16));
                acc[4] += wgt * bf2f((u16)(vv.z & 0xffff));
                acc[5] += wgt * bf2f((u16)(vv.z >> 16));
                acc[6] += wgt * bf2f((u16)(vv.w & 0xffff));
                acc[7] += wgt * bf2f((u16)(vv.w >> 16));
            }
        }
    }
    uint4 r;
    r.x = (unsigned)f2bf(acc[0] * inv_es) | ((unsigned)f2bf(acc[1] * inv_es) << 16);
    r.y = (unsigned)f2bf(acc[2] * inv_es) | ((unsigned)f2bf(acc[3] * inv_es) << 16);
    r.z = (unsigned)f2bf(acc[4] * inv_es) | ((unsigned)f2bf(acc[5] * inv_es) << 16);
    r.w = (unsigned)f2bf(acc[6] * inv_es) | ((unsigned)f2bf(acc[7] * inv_es) << 16);
    *(uint4*)(out + (size_t)bj * CDIM + h * HEAD_DIM + d8) = r;
}

// ---------------------------------------------------------------------------
// launcher
// ---------------------------------------------------------------------------
extern "C" void kernel_launch(void* const* d_in, const int* in_sizes, int n_in,
                              void* d_out, int out_size, void* d_ws, size_t ws_size,
                              hipStream_t stream)
{
    const float* bev   = (const float*)d_in[0];
    const float* lidar = (const float*)d_in[1];
    const float* Wv    = (const float*)d_in[2];
    const float* bv    = (const float*)d_in[3];
    const float* Woff  = (const float*)d_in[4];
    const float* boff  = (const float*)d_in[5];
    const float* Waw   = (const float*)d_in[6];
    const float* baw   = (const float*)d_in[7];
    const float* Wout  = (const float*)d_in[8];
    const float* bout  = (const float*)d_in[9];
    const float* ln1g  = (const float*)d_in[10];
    const float* ln1b  = (const float*)d_in[11];
    const float* W1    = (const float*)d_in[12];
    const float* W2    = (const float*)d_in[13];
    const float* ln2g  = (const float*)d_in[14];
    const float* ln2b  = (const float*)d_in[15];
    const float* peW1  = (const float*)d_in[16];
    const float* peg   = (const float*)d_in[17];
    const float* peb   = (const float*)d_in[18];
    const float* pem   = (const float*)d_in[19];
    const float* pev   = (const float*)d_in[20];
    const float* peW2  = (const float*)d_in[21];

    const size_t NC = (size_t)BN_TOT * CDIM;    // 16,777,216
    const size_t WSZ = 512 * 512;               // one square weight

    char* base = (char*)d_ws;
    u16* q      = (u16*)base;                           // NC bf16 (residual stream)
    u16* actA   = (u16*)(base + NC * 2);                // NC bf16 (v / h / pe-hidden)
    u16* actB   = (u16*)(base + NC * 4);                // NC bf16 (sampled)
    u16* wt     = (u16*)(base + NC * 6);                // 25 x 512x512 bf16
    u16* wtv    = wt;                                   // [6]
    u16* wtout  = wt + 6 * WSZ;                         // [6]
    u16* wt1    = wt + 12 * WSZ;                        // [6]
    u16* wt2    = wt + 18 * WSZ;                        // [6]
    u16* wtpe   = wt + 24 * WSZ;                        // [1]
    u16* offawt = wt + 25 * WSZ;                        // 6 x 96x512 bf16
    u16* offb   = offawt + 6 * 96 * 512;                // BN x 64 bf16
    u16* awb    = offb + (size_t)BN_TOT * 64;           // BN x 32 bf16
    float* refb = (float*)(awb + (size_t)BN_TOT * 32);  // BN x 2 fp32
    int* mask   = (int*)(refb + (size_t)BN_TOT * 2);
    int* order  = mask + BN_TOT;
    int* nvalid = order + BN_TOT;

    // d_out doubles as scratch until final scatter:
    u16* qpos_bf = (u16*)d_out;                         // NC bf16 (first half)
    u16* featT   = (u16*)d_out + NC;                    // NC bf16 (second half)

    dim3 blk328(32, 8);
    dim3 gemm_grid(4, 256);        // 128x128 tiles
    dim3 offaw_grid(1, 256);
    int  ln_grid = BN_TOT / 64;    // 512 blocks of 64 rows

    // voxelize
    mask_kernel<<<BN_TOT / 256, 256, 0, stream>>>(lidar, mask);
    order_kernel<<<BDIM, 256, 0, stream>>>(mask, order, nvalid);
    ref_kernel<<<BN_TOT / 256, 256, 0, stream>>>(order, nvalid, refb);
    pack_q_kernel<<<dim3(NDIM / 32, CDIM / 32, BDIM), blk328, 0, stream>>>(lidar, order, nvalid, q);
    bev_conv_kernel<<<dim3(NDIM / 32, CDIM / 32, BDIM), blk328, 0, stream>>>(bev, featT);

    // hoisted weight conversions (all layers at once)
    tconv_b_kernel<<<dim3(16, 16, 6), blk328, 0, stream>>>(Wv,   wtv);
    tconv_b_kernel<<<dim3(16, 16, 6), blk328, 0, stream>>>(Wout, wtout);
    tconv_b_kernel<<<dim3(16, 16, 6), blk328, 0, stream>>>(W1,   wt1);
    tconv_b_kernel<<<dim3(16, 16, 6), blk328, 0, stream>>>(W2,   wt2);
    tconv_b_kernel<<<dim3(16, 16, 1), blk328, 0, stream>>>(peW2, wtpe);
    tconv_offaw_b_kernel<<<dim3(16, 3, 6), blk328, 0, stream>>>(Woff, Waw, offawt);

    // positional embedding: qpos_bf = relu(BN(ref@peW1)) @ peW2
    pe_hidden_kernel<<<BN_TOT, 128, 0, stream>>>(refb, peW1, peg, peb, pem, pev, actA);
    gemm_bf16<<<gemm_grid, 256, 0, stream>>>(actA, wtpe, nullptr, qpos_bf, 0);

    for (int i = 0; i < LNUM; ++i) {
        // off/aw = (q + qpos) @ [Woff|Waw] + bias   (x fused on the fly)
        gemm_offaw<<<offaw_grid, 256, 0, stream>>>(q, qpos_bf,
                                                   offawt + (size_t)i * 96 * 512,
                                                   boff + i * 64, baw + i * 32, offb, awb);
        // v = featT @ Wv + bv -> actA
        gemm_bf16<<<gemm_grid, 256, 0, stream>>>(featT, wtv + (size_t)i * WSZ,
                                                 bv + i * CDIM, actA, 0);
        // sampled -> actB
        sample_kernel<<<BN_TOT / 4, 256, 0, stream>>>(refb, offb, awb, actA, actB);
        // q = LN1(sampled @ Wout + bout + q)
        gemm_ln<<<ln_grid, 512, 0, stream>>>(actB, wtout + (size_t)i * WSZ, bout + i * CDIM,
                                             q, ln1g + i * CDIM, ln1b + i * CDIM, q);
        // h = relu(q @ W1) -> actA
        gemm_bf16<<<gemm_grid, 256, 0, stream>>>(q, wt1 + (size_t)i * WSZ, nullptr, actA, 1);
        // q = LN2(h @ W2 + q)
        gemm_ln<<<ln_grid, 512, 0, stream>>>(actA, wt2 + (size_t)i * WSZ, nullptr,
                                             q, ln2g + i * CDIM, ln2b + i * CDIM, q);
    }

    // scatter back to dense (B, C, H, W) — overwrites all of d_out
    scatter_kernel<<<dim3(NDIM / 32, CDIM / 32, BDIM), blk328, 0, stream>>>(
        q, order, nvalid, (float*)d_out);
}